// Round 1
// 187.575 us; speedup vs baseline: 1.0686x; 1.0686x over previous
//
#include <hip/hip_runtime.h>
#include <hip/hip_bf16.h>

// GATNet 2-layer GAT, N=50000, E=800000 (+N self loops). f32 in/out, bf16 MFMA.
// Round-15: (a) gemm1 fused into agg0 (block = 16 nodes, 16 lanes/node; ELU
// rows staged in LDS feed a 4-wave MFMA epilogue) -> h1in 25.6MB round-trip
// and one launch removed. (b) k_gz removed: gcur is count-only, zero-init via
// hipMemsetAsync. Rest = r14 (fp8 h0, bucketed CSR, packed bf16 weights).

typedef __attribute__((ext_vector_type(8))) short bf8_t;   // 8 x bf16 (4 VGPRs)
typedef __attribute__((ext_vector_type(4))) float f4_t;
typedef __attribute__((ext_vector_type(2))) float f2_t;

#define NBUCK 256      // bucket table size (used buckets = (N+255)>>8 = 196)
#define BCAP  8192     // per-bucket capacity (expected ~4343, uniform random)

__device__ inline short f2bf(float f) {
    return (short)__builtin_bit_cast(unsigned short, __float2bfloat16(f));
}
__device__ inline float blo(unsigned int p) { return __uint_as_float(p << 16); }
__device__ inline float bhi(unsigned int p) { return __uint_as_float(p & 0xffff0000u); }
__device__ inline float lrexp(float e) {
    e = (e > 0.f) ? e : 0.2f * e;          // leaky_relu(0.2); |e|<~12 -> exp safe
    return __expf(e);
}

// ---- fused: weight pack (blocks 0..63)  |  edge bucketing (blocks 64..) ----
__global__ __launch_bounds__(256) void k_initbucket(
    const int* __restrict__ ei,
    const float* __restrict__ W0, const float* __restrict__ lW0,
    const float* __restrict__ W1, const float* __restrict__ lW1,
    const float* __restrict__ b0, const float* __restrict__ lb0,
    const float* __restrict__ b1, const float* __restrict__ lb1,
    short* __restrict__ Wp0, short* __restrict__ lWp0,
    short* __restrict__ Wp1, short* __restrict__ lWp1,
    float* __restrict__ bc0, float* __restrict__ bc1,
    int* __restrict__ gcur,
    unsigned int* __restrict__ bucketed, int E, int T) {
    __shared__ int hist[NBUCK];
    __shared__ int gbase[NBUCK];
    int tid = threadIdx.x;

    if (blockIdx.x < 64) {                 // ---- weight/bias pack ----
        int i = blockIdx.x * 256 + tid;    // 0..16383
        {
            int j = i & 7, lane = (i >> 3) & 63, kc = i >> 9;
            int kb = kc & 3, ct = kc >> 2;
            int src = (ct * 16 + (lane & 15)) * 128 + kb * 32 + (lane >> 4) * 8 + j;
            Wp0[i]  = f2bf(W0[src]);
            lWp0[i] = f2bf(lW0[src]);
            if (i < 4096) {
                Wp1[i]  = f2bf(W1[src]);
                lWp1[i] = f2bf(lW1[src]);
            }
        }
        if (i < 128) bc0[i] = b0[i] + lb0[i];
        else if (i < 160) bc1[i - 128] = b1[i - 128] + lb1[i - 128];
        return;
    }

    // ---- bucketing: 2048 edges/block, LDS-ranked runs ----
    int bb = blockIdx.x - 64;
    hist[tid] = 0;
    __syncthreads();
    int base = bb * 2048;
    unsigned int pk[8]; int rk[8]; int bk[8];
    #pragma unroll
    for (int j = 0; j < 8; j++) {
        int e = base + j * 256 + tid;
        if (e < T) {
            int src, dst;
            if (e < E) { src = ei[e]; dst = ei[E + e]; }
            else       { src = e - E; dst = src; }          // self-loops
            int b = dst >> 8;
            pk[j] = ((unsigned int)dst << 16) | (unsigned int)src;
            bk[j] = b;
            rk[j] = atomicAdd(&hist[b], 1);
        } else bk[j] = -1;
    }
    __syncthreads();
    int h = hist[tid];
    if (h > 0) gbase[tid] = tid * BCAP + atomicAdd(&gcur[tid], h);
    __syncthreads();
    #pragma unroll
    for (int j = 0; j < 8; j++)
        if (bk[j] >= 0)
            bucketed[gbase[bk[j]] + rk[j]] = pk[j];
}

// ---------------- fused: CSR fill (blocks 0..NBK-1) | GEMM0 (rest) ----------
// fill: self-scans bucket counts, then per-node LDS histogram+scan ->
// rowstart slice + esrc fill. gemm0: h0 fp8-e4m3 + skip0 bf16 + att0 logits.

#define TSTR 136   // short-tile row stride (272B); byte-tile row stride 136B

__global__ __launch_bounds__(256) void k_fillgemm0(
    const unsigned int* __restrict__ bucketed, const int* __restrict__ gcur,
    int* __restrict__ rowstart,
    unsigned short* __restrict__ esrc,
    const float* __restrict__ x,
    const short* __restrict__ Wp0, const short* __restrict__ lWp0,
    const float* __restrict__ as0, const float* __restrict__ ad0,
    unsigned char* __restrict__ h0f8, __hip_bfloat16* __restrict__ skipb,
    float* __restrict__ a0s, float* __restrict__ a0d, int N) {
    __shared__ int ihist[256];
    __shared__ int incl[256];
    __shared__ short tile[4][16 * TSTR];
    __shared__ unsigned char t8[4][16 * 136];
    int NBK = (N + 255) >> 8;

    if ((int)blockIdx.x < NBK) {           // ---- CSR fill ----
        int b = blockIdx.x, t = threadIdx.x;
        int nodebase = b << 8;
        // self-scan of bucket counts
        int cntt = gcur[t];
        incl[t] = cntt;
        __syncthreads();
        for (int off = 1; off < 256; off <<= 1) {
            int tv = (t >= off) ? incl[t - off] : 0;
            __syncthreads();
            incl[t] += tv;
            __syncthreads();
        }
        int rbase = (b > 0) ? incl[b - 1] : 0;
        if (b == 0 && t == 255) rowstart[N] = incl[255];
        int used = gcur[b];
        const unsigned int* bk = bucketed + (size_t)b * BCAP;
        __syncthreads();
        // per-node histogram
        ihist[t] = 0;
        __syncthreads();
        for (int i = t; i < used; i += 256)
            atomicAdd(&ihist[(bk[i] >> 16) - nodebase], 1);
        __syncthreads();
        int v = ihist[t];
        incl[t] = v;
        __syncthreads();
        for (int off = 1; off < 256; off <<= 1) {
            int tv = (t >= off) ? incl[t - off] : 0;
            __syncthreads();
            incl[t] += tv;
            __syncthreads();
        }
        int myexcl = incl[t] - v;
        int node = nodebase + t;
        if (node < N) rowstart[node] = rbase + myexcl;
        __syncthreads();
        ihist[t] = myexcl;                 // reuse as fill cursor
        __syncthreads();
        for (int i = t; i < used; i += 256) {
            unsigned int p = bk[i];
            int pos = atomicAdd(&ihist[(p >> 16) - nodebase], 1);
            esrc[rbase + pos] = (unsigned short)(p & 0xffffu);
        }
        return;
    }

    // ---- GEMM0 + fused att0 ----
    int bx = blockIdx.x - NBK;
    int wv = threadIdx.x >> 6, lane = threadIdx.x & 63;
    int rowbase = bx * 64 + wv * 16;
    int m = lane & 15, q = lane >> 4;
    int arow = rowbase + m; if (arow >= N) arow = N - 1;
    bf8_t a[4];
    #pragma unroll
    for (int kb = 0; kb < 4; kb++) {
        const float4* px = (const float4*)(x + (size_t)arow * 128 + kb * 32 + q * 8);
        float4 lo = px[0], hi = px[1];
        bf8_t f;
        f[0] = f2bf(lo.x); f[1] = f2bf(lo.y); f[2] = f2bf(lo.z); f[3] = f2bf(lo.w);
        f[4] = f2bf(hi.x); f[5] = f2bf(hi.y); f[6] = f2bf(hi.z); f[7] = f2bf(hi.w);
        a[kb] = f;
    }
    float sacc[4][4], dacc[4][4];
    #pragma unroll
    for (int h = 0; h < 4; h++)
        #pragma unroll
        for (int r = 0; r < 4; r++) { sacc[h][r] = 0.f; dacc[h][r] = 0.f; }
    short* tl = tile[wv];
    unsigned char* t8l = t8[wv];
    int r4 = lane >> 2, qt = lane & 3;     // drain mapping: row, quarter
    int drow = rowbase + r4;

    // phase 1: h0 (cts 0..7) as fp8-e4m3 + att accumulation
    #pragma unroll
    for (int ct = 0; ct < 8; ct++) {
        f4_t acc = {0.f, 0.f, 0.f, 0.f};
        #pragma unroll
        for (int kb = 0; kb < 4; kb++) {
            bf8_t b = *(const bf8_t*)(Wp0 + (((ct * 4 + kb) * 64 + lane) << 3));
            acc = __builtin_amdgcn_mfma_f32_16x16x32_bf16(a[kb], b, acc, 0, 0, 0);
        }
        int hd = ct >> 1;
        float ws = as0[ct * 16 + m], wd = ad0[ct * 16 + m];
        #pragma unroll
        for (int r = 0; r < 4; r++) {
            sacc[hd][r] += acc[r] * ws;
            dacc[hd][r] += acc[r] * wd;
            int pk8 = __builtin_amdgcn_cvt_pk_fp8_f32(acc[r], acc[r], 0, false);
            t8l[(q * 4 + r) * 136 + ct * 16 + m] = (unsigned char)(pk8 & 0xff);
        }
    }
    if (drow < N) {
        const unsigned char* sp8 = t8l + r4 * 136 + qt * 32;   // 8B-aligned
        uint2 w0 = ((const uint2*)sp8)[0];
        uint2 w1 = ((const uint2*)sp8)[1];
        uint2 w2 = ((const uint2*)sp8)[2];
        uint2 w3 = ((const uint2*)sp8)[3];
        uint4 o0 = make_uint4(w0.x, w0.y, w1.x, w1.y);
        uint4 o1 = make_uint4(w2.x, w2.y, w3.x, w3.y);
        unsigned char* dst = h0f8 + (size_t)drow * 128 + qt * 32;
        *(uint4*)dst = o0;
        *(uint4*)(dst + 16) = o1;
    }

    // phase 2: skip (cts 8..15) bf16 -> short tile, drain to skipb
    #pragma unroll
    for (int ct = 0; ct < 8; ct++) {
        f4_t acc = {0.f, 0.f, 0.f, 0.f};
        #pragma unroll
        for (int kb = 0; kb < 4; kb++) {
            bf8_t b = *(const bf8_t*)(lWp0 + (((ct * 4 + kb) * 64 + lane) << 3));
            acc = __builtin_amdgcn_mfma_f32_16x16x32_bf16(a[kb], b, acc, 0, 0, 0);
        }
        #pragma unroll
        for (int r = 0; r < 4; r++)
            tl[(q * 4 + r) * TSTR + ct * 16 + m] = f2bf(acc[r]);
    }
    if (drow < N) {
        short* dst = (short*)skipb + (size_t)drow * 128 + qt * 32;
        const short* srcp = tl + r4 * TSTR + qt * 32;
        #pragma unroll
        for (int s = 0; s < 4; s++)
            *(uint4*)(dst + s * 8) = *(const uint4*)(srcp + s * 8);
    }

    // att logits: reduce over the 16 m-lanes
    #pragma unroll
    for (int h = 0; h < 4; h++)
        #pragma unroll
        for (int r = 0; r < 4; r++) {
            float s = sacc[h][r], d = dacc[h][r];
            #pragma unroll
            for (int off = 1; off < 16; off <<= 1) {
                s += __shfl_xor(s, off);
                d += __shfl_xor(d, off);
            }
            sacc[h][r] = s; dacc[h][r] = d;
        }
    if (m < 4) {
        #pragma unroll
        for (int r = 0; r < 4; r++) {
            int row = rowbase + q * 4 + r;
            if (row < N) {
                float sv = (m == 0) ? sacc[0][r] : (m == 1) ? sacc[1][r]
                         : (m == 2) ? sacc[2][r] : sacc[3][r];
                float dv = (m == 0) ? dacc[0][r] : (m == 1) ? dacc[1][r]
                         : (m == 2) ? dacc[2][r] : dacc[3][r];
                a0s[row * 4 + m] = sv;
                a0d[row * 4 + m] = dv;
            }
        }
    }
}

// ------- fused agg0 + ELU + gemm1(+att1): block = 16 nodes, 16 lanes/node ---
// Aggregation: lane t of a node owns channels t*8..t*8+7 (head t>>2), so den
// and acc are per-head with NO cross-lane reduce. ELU rows -> LDS tile, which
// is the MFMA A operand: 4 waves split the 4 ct-phases of gemm1 (Wp1 ct0/ct1,
// lWp1 ct0/ct1), att1 partials combined through a tiny LDS slab.

__global__ __launch_bounds__(256) void k_aggfuse(
    const int* __restrict__ rowstart, const unsigned short* __restrict__ esrc,
    const uint2* __restrict__ h0f8,                    // row = 16 uint2 (128 fp8)
    const float* __restrict__ a0s, const float* __restrict__ a0d,
    const float* __restrict__ bc0,                     // bias0+linb0 [128]
    const unsigned int* __restrict__ skip0,            // skip0 bf16, row=64 uints
    const short* __restrict__ Wp1, const short* __restrict__ lWp1,
    const float* __restrict__ as1, const float* __restrict__ ad1,
    __hip_bfloat16* __restrict__ h1, float* __restrict__ outskip,
    float* __restrict__ a1s, float* __restrict__ a1d, int n) {
    __shared__ __align__(16) short hrow[16][136];      // ELU rows (bf16)
    __shared__ __align__(16) short th[16 * 40];        // h1 tile
    __shared__ __align__(16) float ts[16 * 36];        // skip tile
    __shared__ float satt[2][16], datt[2][16];

    int tid = threadIdx.x;
    int nl = tid >> 4, t = tid & 15, hd = t >> 2;
    int rowbase = blockIdx.x << 4;
    int node = rowbase + nl;

    if (node < n) {
        float ad = a0d[node * 4 + hd];
        int s0 = rowstart[node], s1 = rowstart[node + 1];
        float den = 0.f;
        float acc[8];
        #pragma unroll
        for (int k = 0; k < 8; k++) acc[k] = 0.f;
        int i = s0;
        for (; i + 3 < s1; i += 4) {                   // 4 edges in flight
            int sE[4]; float e[4]; uint2 p[4];
            #pragma unroll
            for (int j = 0; j < 4; j++) sE[j] = esrc[i + j];
            #pragma unroll
            for (int j = 0; j < 4; j++) e[j] = a0s[sE[j] * 4 + hd] + ad;
            #pragma unroll
            for (int j = 0; j < 4; j++) p[j] = h0f8[(size_t)sE[j] * 16 + t];
            #pragma unroll
            for (int j = 0; j < 4; j++) {
                float wgt = lrexp(e[j]);
                den += wgt;
                f2_t c01 = __builtin_amdgcn_cvt_pk_f32_fp8(p[j].x, false);
                f2_t c23 = __builtin_amdgcn_cvt_pk_f32_fp8(p[j].x, true);
                f2_t c45 = __builtin_amdgcn_cvt_pk_f32_fp8(p[j].y, false);
                f2_t c67 = __builtin_amdgcn_cvt_pk_f32_fp8(p[j].y, true);
                acc[0] += wgt * c01.x; acc[1] += wgt * c01.y;
                acc[2] += wgt * c23.x; acc[3] += wgt * c23.y;
                acc[4] += wgt * c45.x; acc[5] += wgt * c45.y;
                acc[6] += wgt * c67.x; acc[7] += wgt * c67.y;
            }
        }
        for (; i < s1; ++i) {
            int s = esrc[i];
            float wgt = lrexp(a0s[s * 4 + hd] + ad);
            uint2 p = h0f8[(size_t)s * 16 + t];
            den += wgt;
            f2_t c01 = __builtin_amdgcn_cvt_pk_f32_fp8(p.x, false);
            f2_t c23 = __builtin_amdgcn_cvt_pk_f32_fp8(p.x, true);
            f2_t c45 = __builtin_amdgcn_cvt_pk_f32_fp8(p.y, false);
            f2_t c67 = __builtin_amdgcn_cvt_pk_f32_fp8(p.y, true);
            acc[0] += wgt * c01.x; acc[1] += wgt * c01.y;
            acc[2] += wgt * c23.x; acc[3] += wgt * c23.y;
            acc[4] += wgt * c45.x; acc[5] += wgt * c45.y;
            acc[6] += wgt * c67.x; acc[7] += wgt * c67.y;
        }
        float inv = 1.0f / (den + 1e-16f);
        uint4 sp = *(const uint4*)(skip0 + (size_t)node * 64 + t * 4);
        int c0 = t * 8;
        float o[8];
        o[0] = acc[0] * inv + blo(sp.x) + bc0[c0 + 0];
        o[1] = acc[1] * inv + bhi(sp.x) + bc0[c0 + 1];
        o[2] = acc[2] * inv + blo(sp.y) + bc0[c0 + 2];
        o[3] = acc[3] * inv + bhi(sp.y) + bc0[c0 + 3];
        o[4] = acc[4] * inv + blo(sp.z) + bc0[c0 + 4];
        o[5] = acc[5] * inv + bhi(sp.z) + bc0[c0 + 5];
        o[6] = acc[6] * inv + blo(sp.w) + bc0[c0 + 6];
        o[7] = acc[7] * inv + bhi(sp.w) + bc0[c0 + 7];
        #pragma unroll
        for (int k = 0; k < 8; k++)
            o[k] = (o[k] > 0.f) ? o[k] : (__expf(o[k]) - 1.f);  // ELU
        uint4 res;
        res.x = (unsigned int)(unsigned short)f2bf(o[0]) | ((unsigned int)(unsigned short)f2bf(o[1]) << 16);
        res.y = (unsigned int)(unsigned short)f2bf(o[2]) | ((unsigned int)(unsigned short)f2bf(o[3]) << 16);
        res.z = (unsigned int)(unsigned short)f2bf(o[4]) | ((unsigned int)(unsigned short)f2bf(o[5]) << 16);
        res.w = (unsigned int)(unsigned short)f2bf(o[6]) | ((unsigned int)(unsigned short)f2bf(o[7]) << 16);
        *(uint4*)&hrow[nl][t * 8] = res;
    } else {
        *(uint4*)&hrow[nl][t * 8] = make_uint4(0u, 0u, 0u, 0u);
    }
    __syncthreads();

    // ---- gemm1 epilogue: wave wv handles (Wp1/lWp1, ct = wv&1) ----
    int wv = tid >> 6, lane = tid & 63;
    int m = lane & 15, q = lane >> 4;
    bf8_t a[4];
    #pragma unroll
    for (int kb = 0; kb < 4; kb++)
        a[kb] = *(const bf8_t*)&hrow[m][kb * 32 + q * 8];
    int ct = wv & 1;
    const short* Wt = (wv < 2) ? Wp1 : lWp1;
    f4_t acc = {0.f, 0.f, 0.f, 0.f};
    #pragma unroll
    for (int kb = 0; kb < 4; kb++) {
        bf8_t b = *(const bf8_t*)(Wt + (((ct * 4 + kb) * 64 + lane) << 3));
        acc = __builtin_amdgcn_mfma_f32_16x16x32_bf16(a[kb], b, acc, 0, 0, 0);
    }
    if (wv < 2) {                                      // h1 bf16 + att partials
        float wsv = as1[ct * 16 + m], wdv = ad1[ct * 16 + m];
        #pragma unroll
        for (int r = 0; r < 4; r++) {
            th[(q * 4 + r) * 40 + ct * 16 + m] = f2bf(acc[r]);
            float s = acc[r] * wsv, d = acc[r] * wdv;
            #pragma unroll
            for (int off = 1; off < 16; off <<= 1) {
                s += __shfl_xor(s, off);
                d += __shfl_xor(d, off);
            }
            if (m == 0) { satt[ct][q * 4 + r] = s; datt[ct][q * 4 + r] = d; }
        }
    } else {                                           // skip (f32)
        #pragma unroll
        for (int r = 0; r < 4; r++)
            ts[(q * 4 + r) * 36 + ct * 16 + m] = acc[r];
    }
    __syncthreads();

    if (tid < 64) {                                    // drain h1 (16 x 64B)
        int row = tid >> 2, qt = tid & 3;
        if (rowbase + row < n)
            *(uint4*)((short*)h1 + (size_t)(rowbase + row) * 32 + qt * 8) =
                *(const uint4*)&th[row * 40 + qt * 8];
    } else if (tid < 192) {                            // drain skip1 (16 x 128B)
        int i2 = tid - 64, row = i2 >> 3, qt = i2 & 7;
        if (rowbase + row < n)
            *(uint4*)(outskip + (size_t)(rowbase + row) * 32 + qt * 4) =
                *(const uint4*)&ts[row * 36 + qt * 4];
    } else if (tid < 208) {                            // att1 logits
        int r2 = tid - 192;
        if (rowbase + r2 < n) {
            a1s[rowbase + r2] = satt[0][r2] + satt[1][r2];
            a1d[rowbase + r2] = datt[0][r2] + datt[1][r2];
        }
    }
}

// ---------- aggregation layer 1: 16-lane edge groups, 4 edges in flight -----

__global__ __launch_bounds__(256) void k_agg1(
    const int* __restrict__ rowstart, const unsigned short* __restrict__ esrc,
    const __hip_bfloat16* __restrict__ h1,
    const float* __restrict__ a1s, const float* __restrict__ a1d,
    const float* __restrict__ bc1,                     // bias1+linb1 [32]
    float* __restrict__ out, int n) {
    int node = (blockIdx.x * 256 + threadIdx.x) >> 6;
    int lane = threadIdx.x & 63;
    if (node >= n) return;
    int g = lane >> 4, t = lane & 15;
    float ad = a1d[node];
    int s0 = rowstart[node], s1 = rowstart[node + 1];
    const unsigned int* h1w = (const unsigned int*)h1;  // row = 16 uints
    float den = 0.f, acc0 = 0.f, acc1 = 0.f;
    int i = s0 + g;
    for (; i + 12 < s1; i += 16) {             // 4 edges/group in flight
        int sE[4]; float e[4]; unsigned int p[4];
        #pragma unroll
        for (int j = 0; j < 4; j++) sE[j] = esrc[i + 4 * j];
        #pragma unroll
        for (int j = 0; j < 4; j++) e[j] = a1s[sE[j]] + ad;
        #pragma unroll
        for (int j = 0; j < 4; j++) p[j] = h1w[(size_t)sE[j] * 16 + t];
        #pragma unroll
        for (int j = 0; j < 4; j++) {
            float wgt = lrexp(e[j]);
            den += wgt;
            acc0 += wgt * blo(p[j]);
            acc1 += wgt * bhi(p[j]);
        }
    }
    for (; i < s1; i += 4) {
        int s = esrc[i];
        float wv = lrexp(a1s[s] + ad);
        unsigned int p = h1w[(size_t)s * 16 + t];
        den += wv; acc0 += wv * blo(p); acc1 += wv * bhi(p);
    }
    acc0 += __shfl_xor(acc0, 16); acc0 += __shfl_xor(acc0, 32);
    acc1 += __shfl_xor(acc1, 16); acc1 += __shfl_xor(acc1, 32);
    den  += __shfl_xor(den, 16);  den  += __shfl_xor(den, 32);
    if (g == 0) {
        float inv = 1.0f / (den + 1e-16f);
        int c0 = t * 2;
        size_t idx = (size_t)node * 32 + c0;
        float2 sk = *(const float2*)(out + idx);     // skip1
        float2 r;
        r.x = acc0 * inv + sk.x + bc1[c0];
        r.y = acc1 * inv + sk.y + bc1[c0 + 1];
        *(float2*)(out + idx) = r;
    }
}

// ---------------- launch ----------------

extern "C" void kernel_launch(void* const* d_in, const int* in_sizes, int n_in,
                              void* d_out, int out_size, void* d_ws, size_t ws_size,
                              hipStream_t stream) {
    const float* x   = (const float*)d_in[0];
    const int*   ei  = (const int*)d_in[1];
    const float* W0  = (const float*)d_in[2];
    const float* as0 = (const float*)d_in[3];
    const float* ad0 = (const float*)d_in[4];
    const float* b0  = (const float*)d_in[5];
    const float* lW0 = (const float*)d_in[6];
    const float* lb0 = (const float*)d_in[7];
    const float* W1  = (const float*)d_in[8];
    const float* as1 = (const float*)d_in[9];
    const float* ad1 = (const float*)d_in[10];
    const float* b1  = (const float*)d_in[11];
    const float* lW1 = (const float*)d_in[12];
    const float* lb1 = (const float*)d_in[13];
    float* out = (float*)d_out;

    const int N = in_sizes[0] / 128;
    const int E = in_sizes[1] / 2;
    const int T = E + N;
    const int NBK  = (N + 255) >> 8;        // used buckets (196)
    const int NBBK = (T + 2047) / 2048;     // bucket blocks (416)

    // workspace carve-up (256B aligned)
    char* w = (char*)d_ws;
    auto alloc = [&](size_t bytes) -> char* {
        char* p = w; w += (bytes + 255) / 256 * 256; return p;
    };
    int* rowstart  = (int*)alloc((size_t)(N + 1) * 4);
    int* gcur      = (int*)alloc(NBUCK * 4);
    unsigned int* bucketed = (unsigned int*)alloc((size_t)NBUCK * BCAP * 4);
    unsigned short* esrc = (unsigned short*)alloc((size_t)T * 2);
    float* aS      = (float*)alloc((size_t)N * 4 * 4);    // layer0 logits [N,4]
    float* aD      = (float*)alloc((size_t)N * 4 * 4);
    char* hbuf     = alloc((size_t)N * 128);              // h0 fp8 (N*128B)
    __hip_bfloat16* skip0 = (__hip_bfloat16*)alloc((size_t)N * 128 * 2);
    __hip_bfloat16* h1buf = (__hip_bfloat16*)alloc((size_t)N * 32 * 2);
    float* aS1     = (float*)alloc((size_t)N * 4);        // layer1 logits [N]
    float* aD1     = (float*)alloc((size_t)N * 4);
    short* Wp0  = (short*)alloc(16384 * 2);
    short* lWp0 = (short*)alloc(16384 * 2);
    short* Wp1  = (short*)alloc(4096 * 2);
    short* lWp1 = (short*)alloc(4096 * 2);
    float* bc0  = (float*)alloc(128 * 4);
    float* bc1  = (float*)alloc(32 * 4);

    // L1: zero bucket counters (capturable); L2: weight-pack ∥ bucketing
    hipMemsetAsync(gcur, 0, NBUCK * sizeof(int), stream);
    k_initbucket<<<64 + NBBK, 256, 0, stream>>>(ei, W0, lW0, W1, lW1,
                                                b0, lb0, b1, lb1,
                                                Wp0, lWp0, Wp1, lWp1, bc0, bc1,
                                                gcur, bucketed, E, T);
    // L3: CSR fill ∥ gemm0(+att0, fp8 h0, bf16 skip0)
    k_fillgemm0<<<NBK + (N + 63) / 64, 256, 0, stream>>>(
        bucketed, gcur, rowstart, esrc,
        x, Wp0, lWp0, as0, ad0, (unsigned char*)hbuf, skip0, aS, aD, N);
    // L4: agg0 + ELU + gemm1(+att1) fused
    k_aggfuse<<<(N + 15) / 16, 256, 0, stream>>>(
        rowstart, esrc, (const uint2*)hbuf, aS, aD, bc0,
        (const unsigned int*)skip0, Wp1, lWp1, as1, ad1,
        h1buf, out, aS1, aD1, N);
    // L5: agg1 + skip + bias
    k_agg1<<<(N + 3) / 4, 256, 0, stream>>>(rowstart, esrc, h1buf,
                                            aS1, aD1, bc1, out, N);
}